// Round 12
// baseline (250.880 us; speedup 1.0000x reference)
//
#include <hip/hip_runtime.h>
#include <math.h>

// (P, C, NX, NY, NT) = (2, 1, 128, 128, 8), T = 128
// Layout: idx = pp<<17 | X<<10 | Y<<3 | T
// R12 = R11 (246.7 us: exchange-not-recompute, packed fp32 VOP3P math,
// med3 clips, DPP swaps, half-T columns, 768 thr, halo 4) + SPLIT bf16
// q-exchange planes: Lq0/Lq1 staged as bf16x4 in u64 (b64 DS ops) instead
// of fp32x4 (b128). DS cycles/thread/substep 84 -> 60 (-29%), LDS 36->24KB,
// +12 VALU (pack/unpack). Only the EXCHANGED copy of q_new is rounded (own
// q stays fp32; all blocks round identically -> cross-block consistency
// bitwise). m-path extra rounding bounded by ulp(lam) ~ 4e-4.
#define NSITES (2 * 128 * 128 * 8)      // 262144
#define NBLK   256                      // 16 bx * 8 by * 2 pp
#define NSUP   32                       // 32 launches x 4 fused steps = 128
#define TLX    16                       // staged cols x: 8 own + 4+4 halo
#define TLY    24                       // staged cols y: 16 own + 4+4 halo
#define NCOL   (TLX * TLY)              // 384 columns
#define NTHR   (NCOL * 2)               // 768 threads, 2 per column

typedef float v2f __attribute__((ext_vector_type(2)));

union F4 { float4 v; float f[4]; v2f h[2]; };
union U4 { uint4 v; unsigned w[4]; };

// bf16 packing: HW v_cvt_pk_bf16_f32 (RNE, one inst).
__device__ __forceinline__ unsigned pk_bf2(float lo, float hi) {
    unsigned r;
    asm("v_cvt_pk_bf16_f32 %0, %1, %2" : "=v"(r) : "v"(lo), "v"(hi));
    return r;
}
__device__ __forceinline__ float bf_lo(unsigned p) { return __uint_as_float(p << 16); }
__device__ __forceinline__ float bf_hi(unsigned p) { return __uint_as_float(p & 0xFFFF0000u); }

// partner (lane xor 1) exchange via DPP quad_perm [1,0,3,2] — VALU pipe.
// Partner lanes share (lx,ly): all masks pairwise-uniform, partners co-active.
__device__ __forceinline__ float dpp_swap1(float x) {
    return __int_as_float(
        __builtin_amdgcn_mov_dpp(__float_as_int(x), 0xB1, 0xF, 0xF, true));
}

__device__ __forceinline__ float med3(float v, float lo, float hi) {
    return __builtin_amdgcn_fmed3f(v, lo, hi);
}

template <bool FIRST, bool LAST>
__global__ __launch_bounds__(NTHR, 3) void pdhg_col(
    const float* __restrict__ x,
    const float* __restrict__ lam,
    const float* __restrict__ tau_p,
    const float* __restrict__ sigma_p,
    const float* __restrict__ theta_p,
    const unsigned long long* __restrict__ inD1,   // bf16x4 {xb,q0,q1,q2}
    const unsigned long long* __restrict__ inD2,   // fp32x2 {p,x0}
    unsigned long long* __restrict__ outD1,
    unsigned long long* __restrict__ outD2,
    float* __restrict__ out_final)
{
    // single-buffered: every write->read and read->overwrite pair of the same
    // array is separated by >=1 __syncthreads (drains lgkmcnt at s_barrier).
    __shared__ float4 Lxb[NTHR];   // 12 KB  xb fp32x4 (4 T of one chunk)
    __shared__ uint2  Lq0[NTHR];   //  6 KB  NEW q0 bf16x4 (word = T-pair)
    __shared__ uint2  Lq1[NTHR];   //  6 KB  NEW q1 bf16x4

    // XCD-arc swizzle (L2-locality heuristic only)
    const int b  = 32 * (blockIdx.x & 7) + (blockIdx.x >> 3);
    const int pp = b >> 7;
    const int rr = b & 127;
    const int bx = rr >> 3;        // [0,16)
    const int by = rr & 7;         // [0,8)

    const int t   = threadIdx.x;   // [0,768)
    const int tm  = t & 1;         // T-chunk: sites tm*4 .. tm*4+3
    const int col = t >> 1;        // [0,384)
    const int lx  = col / TLY;     // [0,16)
    const int ly  = col - lx * TLY;// [0,24)

    const int X  = ((bx << 3) + lx - 4) & 127;
    const int Y  = ((by << 4) + ly - 4) & 127;

    const int gcol = (pp << 17) | (X << 10) | (Y << 3);   // site idx of T=0

    // x-phase widest region R(3): lx in [1,15), ly in [1,23)
    const bool comp = (lx >= 1) && (lx < 15) && (ly >= 1) && (ly < 23);

    const float L = 3.605551275463989f;  // sqrt(13)
    const float s_sig = (1.f / (1.f + __expf(-sigma_p[0]))) / L;
    const float s_tau = (1.f / (1.f + __expf(-tau_p[0]))) / L;
    const float s_th  =  1.f / (1.f + __expf(-theta_p[0]));
    const float inv1s = 1.f / (1.f + s_sig);

    const v2f sig2   = { s_sig, s_sig };
    const v2f inv1s2 = { inv1s, inv1s };
    const v2f ntau2  = { -s_tau, -s_tau };
    const v2f th2    = { s_th, s_th };

    const int c4 = (gcol >> 2) + tm;   // float4 index of this chunk

    // invariant inputs, loaded unconditionally (lamc needed on full Q(3))
    v2f xnv[2], lamv[2];
    {
        const float4* x4 = (const float4*)x;
        const float4* l4 = (const float4*)lam;
        F4 a;
        a.v = x4[c4];
        xnv[0] = a.h[0]; xnv[1] = a.h[1];
        a.v = l4[c4];
        lamv[0] = a.h[0]; lamv[1] = a.h[1];
    }

    v2f x0v[2], pv[2], q0v[2], q1v[2], q2v[2], xbv[2];
    if (FIRST) {
        #pragma unroll
        for (int k = 0; k < 2; ++k) {
            x0v[k] = xnv[k]; pv[k] = xnv[k]; xbv[k] = xnv[k];
            q0v[k] = (v2f){0.f, 0.f}; q1v[k] = (v2f){0.f, 0.f}; q2v[k] = (v2f){0.f, 0.f};
        }
    } else {
        const uint4* d1 = (const uint4*)inD1;       // 2 sites per uint4
        const int base = (gcol >> 1) + 2 * tm;      // 16B-granule index
        #pragma unroll
        for (int k = 0; k < 2; ++k) {
            U4 a; a.v = d1[base + k];
            xbv[k] = (v2f){ bf_lo(a.w[0]), bf_lo(a.w[2]) };
            q0v[k] = (v2f){ bf_hi(a.w[0]), bf_hi(a.w[2]) };
            q1v[k] = (v2f){ bf_lo(a.w[1]), bf_lo(a.w[3]) };
            q2v[k] = (v2f){ bf_hi(a.w[1]), bf_hi(a.w[3]) };
        }
        if (comp) {
            const float4* d2 = (const float4*)inD2;  // 2 sites per float4
            #pragma unroll
            for (int k = 0; k < 2; ++k) {
                F4 a; a.v = d2[base + k];
                pv[k]  = (v2f){ a.f[0], a.f[2] };
                x0v[k] = (v2f){ a.f[1], a.f[3] };
            }
        } else {
            #pragma unroll
            for (int k = 0; k < 2; ++k) { pv[k] = (v2f){0.f,0.f}; x0v[k] = (v2f){0.f,0.f}; }
        }
    }

    // stage xb for substep(3): S(3) = full tile, unconditional
    {
        F4 s; s.h[0] = xbv[0]; s.h[1] = xbv[1];
        Lxb[t] = s.v;
    }

    // one fused sub-step h:
    //  q-phase  Q(h): lx in [3-h,12+h), ly in [3-h,20+h)  (reads Lxb; stores Lq)
    //  x-phase  R(h): lx in [4-h,12+h), ly in [4-h,20+h)  (reads Lq; stores Lxb
    //                 for next substep — S(h-1) == R(h) — skipped at h==0)
    auto substep = [&](const int h) {
        __syncthreads();
        // -------- Phase A: q-update (packed) --------
        if (lx >= 3 - h && lx < 12 + h && ly >= 3 - h && ly < 20 + h) {
            F4 xp, yp;
            xp.v = Lxb[t + 2 * TLY];
            yp.v = Lxb[t + 2];
            const float xb_tp = dpp_swap1(xbv[0].x);   // partner xb[0] = T+1 wrap
            const v2f tp0 = { xbv[0].y, xbv[1].x };    // xb shifted by +1 in T
            const v2f tp1 = { xbv[1].y, xb_tp };
            #pragma unroll
            for (int k = 0; k < 2; ++k) {
                const v2f t0 = __builtin_elementwise_fma(sig2, xp.h[k] - xbv[k], q0v[k]);
                const v2f t1 = __builtin_elementwise_fma(sig2, yp.h[k] - xbv[k], q1v[k]);
                const v2f t2 = __builtin_elementwise_fma(sig2, (k ? tp1 : tp0) - xbv[k], q2v[k]);
                q0v[k].x = med3(t0.x, -lamv[k].x, lamv[k].x);
                q0v[k].y = med3(t0.y, -lamv[k].y, lamv[k].y);
                q1v[k].x = med3(t1.x, -lamv[k].x, lamv[k].x);
                q1v[k].y = med3(t1.y, -lamv[k].y, lamv[k].y);
                q2v[k].x = med3(t2.x, -lamv[k].x, lamv[k].x);
                q2v[k].y = med3(t2.y, -lamv[k].y, lamv[k].y);
            }
            // exchange copy of NEW q0/q1, bf16-packed (b64 DS):
            // word k = pk(T-pair k) — matches v2f lane order on unpack
            Lq0[t] = make_uint2(pk_bf2(q0v[0].x, q0v[0].y),
                                pk_bf2(q0v[1].x, q0v[1].y));
            Lq1[t] = make_uint2(pk_bf2(q1v[0].x, q1v[0].y),
                                pk_bf2(q1v[1].x, q1v[1].y));
        }
        __syncthreads();
        // -------- Phase B: m-exchange + p/x/xb update (packed) --------
        if (lx >= 4 - h && lx < 12 + h && ly >= 4 - h && ly < 20 + h) {
            const uint2 wx = Lq0[t - 2 * TLY];         // x-1's NEW q0 (bf16) == q0m
            const uint2 wy = Lq1[t - 2];               // y-1's NEW q1 (bf16) == q1m
            const v2f qx0 = { bf_lo(wx.x), bf_hi(wx.x) };
            const v2f qx1 = { bf_lo(wx.y), bf_hi(wx.y) };
            const v2f qy0 = { bf_lo(wy.x), bf_hi(wy.x) };
            const v2f qy1 = { bf_lo(wy.y), bf_hi(wy.y) };
            const float q2_tm = dpp_swap1(q2v[1].y);   // partner NEW q2[3] = T-1 wrap
            const v2f q2m0 = { q2_tm, q2v[0].x };      // NEW q2 shifted by -1 in T
            const v2f q2m1 = { q2v[0].y, q2v[1].x };
            #pragma unroll
            for (int k = 0; k < 2; ++k) {
                v2f pn = __builtin_elementwise_fma(sig2, xbv[k] - xnv[k], pv[k]);
                pn = pn * inv1s2;
                const v2f dv = (((k ? qx1 : qx0) - q0v[k]) + ((k ? qy1 : qy0) - q1v[k]))
                             + ((k ? q2m1 : q2m0) - q2v[k]);
                const v2f x1 = __builtin_elementwise_fma(ntau2, pn + dv, x0v[k]);
                xbv[k] = __builtin_elementwise_fma(th2, x1 - x0v[k], x1);
                x0v[k] = x1; pv[k] = pn;
            }
            if (h > 0) {                               // stage xb for next substep
                F4 s; s.h[0] = xbv[0]; s.h[1] = xbv[1];
                Lxb[t] = s.v;
            }
        }
    };

    substep(3);   // step 4g+1 on 14x22
    substep(2);   // step 4g+2 on 12x20
    substep(1);   // step 4g+3 on 10x18
    substep(0);   // step 4g+4 on  8x16 (own)

    // write authoritative own sites only
    if (lx >= 4 && lx < 12 && ly >= 4 && ly < 20) {
        if (LAST) {
            float4* o4 = (float4*)out_final;
            F4 a;
            a.f[0] = x0v[0].x; a.f[1] = x0v[0].y;
            a.f[2] = x0v[1].x; a.f[3] = x0v[1].y;
            o4[c4] = a.v;
        } else {
            uint4*  o1 = (uint4*)outD1;
            float4* o2 = (float4*)outD2;
            const int base = (gcol >> 1) + 2 * tm;
            #pragma unroll
            for (int k = 0; k < 2; ++k) {
                U4 w;
                w.w[0] = pk_bf2(xbv[k].x, q0v[k].x);
                w.w[1] = pk_bf2(q1v[k].x, q2v[k].x);
                w.w[2] = pk_bf2(xbv[k].y, q0v[k].y);
                w.w[3] = pk_bf2(q1v[k].y, q2v[k].y);
                o1[base + k] = w.v;
                F4 d;
                d.f[0] = pv[k].x; d.f[1] = x0v[k].x;
                d.f[2] = pv[k].y; d.f[3] = x0v[k].y;
                o2[base + k] = d.v;
            }
        }
    }
}

extern "C" void kernel_launch(void* const* d_in, const int* in_sizes, int n_in,
                              void* d_out, int out_size, void* d_ws, size_t ws_size,
                              hipStream_t stream) {
    const float* x   = (const float*)d_in[0];
    const float* lam = (const float*)d_in[1];
    const float* tau = (const float*)d_in[2];
    const float* sig = (const float*)d_in[3];
    const float* th  = (const float*)d_in[4];
    float* out = (float*)d_out;

    // ws layout: D1 (2 slots u64, 4 MB), D2 (2 slots u64, 4 MB)
    unsigned long long* D1 = (unsigned long long*)d_ws;
    unsigned long long* D2 = D1 + 2 * (size_t)NSITES;

    dim3 grid(NBLK), block(NTHR);

    for (int g = 0; g < NSUP; ++g) {
        const size_t si = (size_t)((g + 1) & 1) * NSITES;  // read slot (prev write)
        const size_t so = (size_t)(g & 1) * NSITES;        // write slot
        const unsigned long long *i1 = D1 + si, *i2 = D2 + si;
        unsigned long long *o1 = D1 + so, *o2 = D2 + so;
        if (g == 0) {
            pdhg_col<true, false><<<grid, block, 0, stream>>>(
                x, lam, tau, sig, th, i1, i2, o1, o2, out);
        } else if (g == NSUP - 1) {
            pdhg_col<false, true><<<grid, block, 0, stream>>>(
                x, lam, tau, sig, th, i1, i2, o1, o2, out);
        } else {
            pdhg_col<false, false><<<grid, block, 0, stream>>>(
                x, lam, tau, sig, th, i1, i2, o1, o2, out);
        }
    }
}

// Round 13
// 247.497 us; speedup vs baseline: 1.0137x; 1.0137x over previous
//
#include <hip/hip_runtime.h>
#include <math.h>

// (P, C, NX, NY, NT) = (2, 1, 128, 128, 8), T = 128
// Layout: idx = pp<<17 | X<<10 | Y<<3 | T
// R13 = R11 (246.7 us — session best: exchange-not-recompute, packed fp32
// VOP3P, med3 clips, DPP swaps, half-T columns, 768 thr, halo 4, fp32 LDS
// q-exchange) + pn HOISTED to phase A (thread-local; overlaps LDS latency;
// extra pn on Q\R halo sites is never consumed — bitwise-identical output).
// R12 (bf16 q-exchange) reverted: DS throughput is NOT exposed (R12 +1.7%);
// VALU issue is (R11 coefficient 0.0086 us/inst/launch, matches issue math).
#define NSITES (2 * 128 * 128 * 8)      // 262144
#define NBLK   256                      // 16 bx * 8 by * 2 pp
#define NSUP   32                       // 32 launches x 4 fused steps = 128
#define TLX    16                       // staged cols x: 8 own + 4+4 halo
#define TLY    24                       // staged cols y: 16 own + 4+4 halo
#define NCOL   (TLX * TLY)              // 384 columns
#define NTHR   (NCOL * 2)               // 768 threads, 2 per column

typedef float v2f __attribute__((ext_vector_type(2)));

union F4 { float4 v; float f[4]; v2f h[2]; };
union U4 { uint4 v; unsigned w[4]; };

// bf16 packing: HW v_cvt_pk_bf16_f32 (RNE, one inst) — D1 epilogue only.
__device__ __forceinline__ unsigned pk_bf2(float lo, float hi) {
    unsigned r;
    asm("v_cvt_pk_bf16_f32 %0, %1, %2" : "=v"(r) : "v"(lo), "v"(hi));
    return r;
}
__device__ __forceinline__ float bf_lo(unsigned p) { return __uint_as_float(p << 16); }
__device__ __forceinline__ float bf_hi(unsigned p) { return __uint_as_float(p & 0xFFFF0000u); }

// partner (lane xor 1) exchange via DPP quad_perm [1,0,3,2] — VALU pipe.
// Partner lanes share (lx,ly): all masks pairwise-uniform, partners co-active.
__device__ __forceinline__ float dpp_swap1(float x) {
    return __int_as_float(
        __builtin_amdgcn_mov_dpp(__float_as_int(x), 0xB1, 0xF, 0xF, true));
}

__device__ __forceinline__ float med3(float v, float lo, float hi) {
    return __builtin_amdgcn_fmed3f(v, lo, hi);
}

template <bool FIRST, bool LAST>
__global__ __launch_bounds__(NTHR, 3) void pdhg_col(
    const float* __restrict__ x,
    const float* __restrict__ lam,
    const float* __restrict__ tau_p,
    const float* __restrict__ sigma_p,
    const float* __restrict__ theta_p,
    const unsigned long long* __restrict__ inD1,   // bf16x4 {xb,q0,q1,q2}
    const unsigned long long* __restrict__ inD2,   // fp32x2 {p,x0}
    unsigned long long* __restrict__ outD1,
    unsigned long long* __restrict__ outD2,
    float* __restrict__ out_final)
{
    // single-buffered: every write->read and read->overwrite pair of the same
    // array is separated by >=1 __syncthreads (drains lgkmcnt at s_barrier).
    __shared__ float4 Lxb[NTHR];   // 12 KB  xb fp32x4 (4 T of one chunk)
    __shared__ float4 Lq0[NTHR];   // 12 KB  NEW q0 fp32x4
    __shared__ float4 Lq1[NTHR];   // 12 KB  NEW q1 fp32x4

    // XCD-arc swizzle (L2-locality heuristic only)
    const int b  = 32 * (blockIdx.x & 7) + (blockIdx.x >> 3);
    const int pp = b >> 7;
    const int rr = b & 127;
    const int bx = rr >> 3;        // [0,16)
    const int by = rr & 7;         // [0,8)

    const int t   = threadIdx.x;   // [0,768)
    const int tm  = t & 1;         // T-chunk: sites tm*4 .. tm*4+3
    const int col = t >> 1;        // [0,384)
    const int lx  = col / TLY;     // [0,16)
    const int ly  = col - lx * TLY;// [0,24)

    const int X  = ((bx << 3) + lx - 4) & 127;
    const int Y  = ((by << 4) + ly - 4) & 127;

    const int gcol = (pp << 17) | (X << 10) | (Y << 3);   // site idx of T=0

    // x-phase widest region R(3): lx in [1,15), ly in [1,23)
    const bool comp = (lx >= 1) && (lx < 15) && (ly >= 1) && (ly < 23);

    const float L = 3.605551275463989f;  // sqrt(13)
    const float s_sig = (1.f / (1.f + __expf(-sigma_p[0]))) / L;
    const float s_tau = (1.f / (1.f + __expf(-tau_p[0]))) / L;
    const float s_th  =  1.f / (1.f + __expf(-theta_p[0]));
    const float inv1s = 1.f / (1.f + s_sig);

    const v2f sig2   = { s_sig, s_sig };
    const v2f inv1s2 = { inv1s, inv1s };
    const v2f ntau2  = { -s_tau, -s_tau };
    const v2f th2    = { s_th, s_th };

    const int c4 = (gcol >> 2) + tm;   // float4 index of this chunk

    // invariant inputs, loaded unconditionally (lamc needed on full Q(3))
    v2f xnv[2], lamv[2];
    {
        const float4* x4 = (const float4*)x;
        const float4* l4 = (const float4*)lam;
        F4 a;
        a.v = x4[c4];
        xnv[0] = a.h[0]; xnv[1] = a.h[1];
        a.v = l4[c4];
        lamv[0] = a.h[0]; lamv[1] = a.h[1];
    }

    v2f x0v[2], pv[2], q0v[2], q1v[2], q2v[2], xbv[2];
    if (FIRST) {
        #pragma unroll
        for (int k = 0; k < 2; ++k) {
            x0v[k] = xnv[k]; pv[k] = xnv[k]; xbv[k] = xnv[k];
            q0v[k] = (v2f){0.f, 0.f}; q1v[k] = (v2f){0.f, 0.f}; q2v[k] = (v2f){0.f, 0.f};
        }
    } else {
        const uint4* d1 = (const uint4*)inD1;       // 2 sites per uint4
        const int base = (gcol >> 1) + 2 * tm;      // 16B-granule index
        #pragma unroll
        for (int k = 0; k < 2; ++k) {
            U4 a; a.v = d1[base + k];
            xbv[k] = (v2f){ bf_lo(a.w[0]), bf_lo(a.w[2]) };
            q0v[k] = (v2f){ bf_hi(a.w[0]), bf_hi(a.w[2]) };
            q1v[k] = (v2f){ bf_lo(a.w[1]), bf_lo(a.w[3]) };
            q2v[k] = (v2f){ bf_hi(a.w[1]), bf_hi(a.w[3]) };
        }
        if (comp) {
            const float4* d2 = (const float4*)inD2;  // 2 sites per float4
            #pragma unroll
            for (int k = 0; k < 2; ++k) {
                F4 a; a.v = d2[base + k];
                pv[k]  = (v2f){ a.f[0], a.f[2] };
                x0v[k] = (v2f){ a.f[1], a.f[3] };
            }
        } else {
            #pragma unroll
            for (int k = 0; k < 2; ++k) { pv[k] = (v2f){0.f,0.f}; x0v[k] = (v2f){0.f,0.f}; }
        }
    }

    // stage xb for substep(3): S(3) = full tile, unconditional
    {
        F4 s; s.h[0] = xbv[0]; s.h[1] = xbv[1];
        Lxb[t] = s.v;
    }

    // one fused sub-step h:
    //  q-phase  Q(h): lx in [3-h,12+h), ly in [3-h,20+h)  (reads Lxb; stores Lq;
    //                 ALSO computes pn — thread-local, pre-update xb. Extra
    //                 pn on Q\R sites is never consumed: only phase-B (mask R)
    //                 and the own-site epilogue read p, and Q\R sites never
    //                 re-enter any later R.)
    //  x-phase  R(h): lx in [4-h,12+h), ly in [4-h,20+h)  (reads Lq; stores Lxb
    //                 for next substep — S(h-1) == R(h) — skipped at h==0)
    auto substep = [&](const int h) {
        __syncthreads();
        // -------- Phase A: q-update + pn (packed) --------
        if (lx >= 3 - h && lx < 12 + h && ly >= 3 - h && ly < 20 + h) {
            F4 xp, yp;
            xp.v = Lxb[t + 2 * TLY];
            yp.v = Lxb[t + 2];
            const float xb_tp = dpp_swap1(xbv[0].x);   // partner xb[0] = T+1 wrap
            const v2f tp0 = { xbv[0].y, xbv[1].x };    // xb shifted by +1 in T
            const v2f tp1 = { xbv[1].y, xb_tp };
            #pragma unroll
            for (int k = 0; k < 2; ++k) {
                v2f pn = __builtin_elementwise_fma(sig2, xbv[k] - xnv[k], pv[k]);
                pv[k] = pn * inv1s2;
                const v2f t0 = __builtin_elementwise_fma(sig2, xp.h[k] - xbv[k], q0v[k]);
                const v2f t1 = __builtin_elementwise_fma(sig2, yp.h[k] - xbv[k], q1v[k]);
                const v2f t2 = __builtin_elementwise_fma(sig2, (k ? tp1 : tp0) - xbv[k], q2v[k]);
                q0v[k].x = med3(t0.x, -lamv[k].x, lamv[k].x);
                q0v[k].y = med3(t0.y, -lamv[k].y, lamv[k].y);
                q1v[k].x = med3(t1.x, -lamv[k].x, lamv[k].x);
                q1v[k].y = med3(t1.y, -lamv[k].y, lamv[k].y);
                q2v[k].x = med3(t2.x, -lamv[k].x, lamv[k].x);
                q2v[k].y = med3(t2.y, -lamv[k].y, lamv[k].y);
            }
            F4 s0, s1;
            s0.h[0] = q0v[0]; s0.h[1] = q0v[1];
            s1.h[0] = q1v[0]; s1.h[1] = q1v[1];
            Lq0[t] = s0.v;
            Lq1[t] = s1.v;
        }
        __syncthreads();
        // -------- Phase B: m-exchange + x/xb update (packed) --------
        if (lx >= 4 - h && lx < 12 + h && ly >= 4 - h && ly < 20 + h) {
            F4 qx, qy;
            qx.v = Lq0[t - 2 * TLY];                   // x-1's NEW q0 == q0m (exact)
            qy.v = Lq1[t - 2];                         // y-1's NEW q1 == q1m (exact)
            const float q2_tm = dpp_swap1(q2v[1].y);   // partner NEW q2[3] = T-1 wrap
            const v2f q2m0 = { q2_tm, q2v[0].x };      // NEW q2 shifted by -1 in T
            const v2f q2m1 = { q2v[0].y, q2v[1].x };
            #pragma unroll
            for (int k = 0; k < 2; ++k) {
                const v2f dv = ((qx.h[k] - q0v[k]) + (qy.h[k] - q1v[k]))
                             + ((k ? q2m1 : q2m0) - q2v[k]);
                const v2f x1 = __builtin_elementwise_fma(ntau2, pv[k] + dv, x0v[k]);
                xbv[k] = __builtin_elementwise_fma(th2, x1 - x0v[k], x1);
                x0v[k] = x1;
            }
            if (h > 0) {                               // stage xb for next substep
                F4 s; s.h[0] = xbv[0]; s.h[1] = xbv[1];
                Lxb[t] = s.v;
            }
        }
    };

    substep(3);   // step 4g+1 on 14x22
    substep(2);   // step 4g+2 on 12x20
    substep(1);   // step 4g+3 on 10x18
    substep(0);   // step 4g+4 on  8x16 (own)

    // write authoritative own sites only
    if (lx >= 4 && lx < 12 && ly >= 4 && ly < 20) {
        if (LAST) {
            float4* o4 = (float4*)out_final;
            F4 a;
            a.f[0] = x0v[0].x; a.f[1] = x0v[0].y;
            a.f[2] = x0v[1].x; a.f[3] = x0v[1].y;
            o4[c4] = a.v;
        } else {
            uint4*  o1 = (uint4*)outD1;
            float4* o2 = (float4*)outD2;
            const int base = (gcol >> 1) + 2 * tm;
            #pragma unroll
            for (int k = 0; k < 2; ++k) {
                U4 w;
                w.w[0] = pk_bf2(xbv[k].x, q0v[k].x);
                w.w[1] = pk_bf2(q1v[k].x, q2v[k].x);
                w.w[2] = pk_bf2(xbv[k].y, q0v[k].y);
                w.w[3] = pk_bf2(q1v[k].y, q2v[k].y);
                o1[base + k] = w.v;
                F4 d;
                d.f[0] = pv[k].x; d.f[1] = x0v[k].x;
                d.f[2] = pv[k].y; d.f[3] = x0v[k].y;
                o2[base + k] = d.v;
            }
        }
    }
}

extern "C" void kernel_launch(void* const* d_in, const int* in_sizes, int n_in,
                              void* d_out, int out_size, void* d_ws, size_t ws_size,
                              hipStream_t stream) {
    const float* x   = (const float*)d_in[0];
    const float* lam = (const float*)d_in[1];
    const float* tau = (const float*)d_in[2];
    const float* sig = (const float*)d_in[3];
    const float* th  = (const float*)d_in[4];
    float* out = (float*)d_out;

    // ws layout: D1 (2 slots u64, 4 MB), D2 (2 slots u64, 4 MB)
    unsigned long long* D1 = (unsigned long long*)d_ws;
    unsigned long long* D2 = D1 + 2 * (size_t)NSITES;

    dim3 grid(NBLK), block(NTHR);

    for (int g = 0; g < NSUP; ++g) {
        const size_t si = (size_t)((g + 1) & 1) * NSITES;  // read slot (prev write)
        const size_t so = (size_t)(g & 1) * NSITES;        // write slot
        const unsigned long long *i1 = D1 + si, *i2 = D2 + si;
        unsigned long long *o1 = D1 + so, *o2 = D2 + so;
        if (g == 0) {
            pdhg_col<true, false><<<grid, block, 0, stream>>>(
                x, lam, tau, sig, th, i1, i2, o1, o2, out);
        } else if (g == NSUP - 1) {
            pdhg_col<false, true><<<grid, block, 0, stream>>>(
                x, lam, tau, sig, th, i1, i2, o1, o2, out);
        } else {
            pdhg_col<false, false><<<grid, block, 0, stream>>>(
                x, lam, tau, sig, th, i1, i2, o1, o2, out);
        }
    }
}